// Round 17
// baseline (215.865 us; speedup 1.0000x reference)
//
#include <hip/hip_runtime.h>
#include <hip/hip_fp16.h>

#define NB 64
#define NS 512
#define NH 1024
#define NITERS 10

// -log(512)
#define LOG_INV_NS (-6.238324625039508f)

using half8 = _Float16 __attribute__((ext_vector_type(8)));
using f32x4 = float __attribute__((ext_vector_type(4)));

#define GLOAD_LDS(G, L)                                                  \
  __builtin_amdgcn_global_load_lds(                                      \
      (const __attribute__((address_space(1))) unsigned int*)(G),        \
      (__attribute__((address_space(3))) unsigned int*)(L), 16, 0, 0)

// ---------------------------------------------------------------------------
// Fused GEMM: batched cosine scores, f16 out. 256x256 tile, 512 thr / 8 waves.
// R17: fp32 staged DIRECTLY to LDS via global_load_lds (16B, fire-and-forget,
// counted vmcnt(8)) — no register round-trip, no WAR chain, no staging VALU.
// LDS layout XOR-swizzled (granule ^= (row&7)<<4) via pre-swizzled GLOBAL
// source addresses (linear LDS writes, m173 pattern). MFMA phase reads fp32
// frags (swizzled) and converts to f16 in-register. Row norms accumulated by
// linear readback of each wave's own staged window (swizzle is within-row).
__global__ __launch_bounds__(512) void gemm_fused(
    const float* __restrict__ x, const float* __restrict__ y,
    _Float16* __restrict__ Sh) {
  __shared__ float As32[2][8192];   // [buf][256 rows x 32 cols] fp32, 32 KB
  __shared__ float Bs32[2][8192];
  __shared__ float invA[256], invB[256];

  int blk = blockIdx.x;
  int b = blk & 63;                  // batch; blk%8 = b%8 -> XCD pinned
  int tile = blk >> 6;               // 0..3
  int tm = (tile >> 1) * 256, tn = (tile & 1) * 256;
  int tid = threadIdx.x;
  int wid = tid >> 6, lane = tid & 63;
  int wr = (wid >> 2) * 128;         // {0,128}
  int wc = (wid & 3) * 64;           // {0,64,128,192}
  int fr = lane & 15, fq = lane >> 4;

  // staging geometry: instruction (wid,q) fills LDS floats
  // [wid*1024 + q*256 + lane*4 .. +4) == row wid*32+q*8+(lane>>3), 16B granule
  // (lane&7). Swizzle: granule g holds data col16 = (g&7) ^ (row&7).
  int rql = wid * 32 + (lane >> 3);          // row for q=0
  int colf = 4 * ((lane & 7) ^ (rql & 7));   // float col of this lane's 16B
  const float* xg0 = x + ((size_t)(b * NS + tm + rql)) * NH + colf;
  const float* yg0 = y + ((size_t)(b * NS + tn + rql)) * NH + colf;

  f32x4 acc[8][4] = {};
  float pa[4] = {0.f, 0.f, 0.f, 0.f};   // sumsq partials (A rows rql+8q)
  float pb[4] = {0.f, 0.f, 0.f, 0.f};

#define GSTAGE(CH, BUF)                                                  \
  do {                                                                   \
    int k0g = (CH) * 32;                                                 \
    _Pragma("unroll") for (int q = 0; q < 4; ++q) {                      \
      GLOAD_LDS(xg0 + (size_t)(q * 8) * NH + k0g,                        \
                &As32[BUF][wid * 1024 + q * 256]);                       \
      GLOAD_LDS(yg0 + (size_t)(q * 8) * NH + k0g,                        \
                &Bs32[BUF][wid * 1024 + q * 256]);                       \
    }                                                                    \
  } while (0)

  // prologue: chunk 0 -> buf0, chunk 1 -> buf1 (in flight)
  GSTAGE(0, 0);
  GSTAGE(1, 1);
  asm volatile("s_waitcnt vmcnt(8)" ::: "memory");   // chunk 0 complete
  __builtin_amdgcn_sched_barrier(0);
  __builtin_amdgcn_s_barrier();
  __builtin_amdgcn_sched_barrier(0);

  for (int s = 0; s < 32; ++s) {
    int cur = s & 1;
    const char* bA = (const char*)&As32[cur][0];
    const char* bB = (const char*)&Bs32[cur][0];

    // ---- compute chunk s: frag reads (swizzled) + cvt + MFMA ----
    half8 bf[4];
#pragma unroll
    for (int j = 0; j < 4; ++j) {
      int R = wc + 16 * j + fr;
      unsigned p0 = (unsigned)(R * 128 + fq * 32);
      unsigned sw = (unsigned)((R & 7) << 4);
      float4 b0 = *(const float4*)(bB + (p0 ^ sw));
      float4 b1 = *(const float4*)(bB + ((p0 + 16) ^ sw));
      bf[j] = half8{(_Float16)b0.x, (_Float16)b0.y, (_Float16)b0.z, (_Float16)b0.w,
                    (_Float16)b1.x, (_Float16)b1.y, (_Float16)b1.z, (_Float16)b1.w};
    }
#pragma unroll
    for (int i = 0; i < 8; ++i) {
      int R = wr + 16 * i + fr;
      unsigned p0 = (unsigned)(R * 128 + fq * 32);
      unsigned sw = (unsigned)((R & 7) << 4);
      float4 a0 = *(const float4*)(bA + (p0 ^ sw));
      float4 a1 = *(const float4*)(bA + ((p0 + 16) ^ sw));
      half8 af = half8{(_Float16)a0.x, (_Float16)a0.y, (_Float16)a0.z, (_Float16)a0.w,
                       (_Float16)a1.x, (_Float16)a1.y, (_Float16)a1.z, (_Float16)a1.w};
#pragma unroll
      for (int j = 0; j < 4; ++j)
        acc[i][j] = __builtin_amdgcn_mfma_f32_16x16x32_f16(af, bf[j], acc[i][j], 0, 0, 0);
    }
    // ---- norm partials: linear readback of this wave's staged window ----
    {
      const float4* nA = (const float4*)&As32[cur][wid * 1024];
      const float4* nB = (const float4*)&Bs32[cur][wid * 1024];
#pragma unroll
      for (int q = 0; q < 4; ++q) {
        float4 va = nA[q * 64 + lane];
        float4 vb = nB[q * 64 + lane];
        pa[q] += va.x * va.x + va.y * va.y + va.z * va.z + va.w * va.w;
        pb[q] += vb.x * vb.x + vb.y * vb.y + vb.z * vb.z + vb.w * vb.w;
      }
    }
    // ---- all reads of buf[cur] done -> barrier, then restage it ----
    asm volatile("s_waitcnt lgkmcnt(0)" ::: "memory");
    __builtin_amdgcn_sched_barrier(0);
    __builtin_amdgcn_s_barrier();
    __builtin_amdgcn_sched_barrier(0);
    if (s < 30) GSTAGE(s + 2, cur);
    if (s < 30)
      asm volatile("s_waitcnt vmcnt(8)" ::: "memory");  // chunk s+1 complete
    else
      asm volatile("s_waitcnt vmcnt(0)" ::: "memory");
    __builtin_amdgcn_sched_barrier(0);
    __builtin_amdgcn_s_barrier();
    __builtin_amdgcn_sched_barrier(0);
  }
#undef GSTAGE

  // ---- finalize norms: reduce 8-lane groups (cols), leaders write ----
#pragma unroll
  for (int q = 0; q < 4; ++q) {
#pragma unroll
    for (int mask = 1; mask <= 4; mask <<= 1) {
      pa[q] += __shfl_xor(pa[q], mask, 64);
      pb[q] += __shfl_xor(pb[q], mask, 64);
    }
  }
  if ((lane & 7) == 0) {
    int rbase = wid * 32 + (lane >> 3);
#pragma unroll
    for (int q = 0; q < 4; ++q) {
      invA[rbase + q * 8] = 1.0f / fmaxf(sqrtf(pa[q]), 1e-12f);
      invB[rbase + q * 8] = 1.0f / fmaxf(sqrtf(pb[q]), 1e-12f);
    }
  }
  __syncthreads();

  // Epilogue: S = acc * invA[m] * invB[n], direct f16 stores.
  // C/D layout: col = lane&15 (n), row = (lane>>4)*4 + reg (m).
  _Float16* Sb = Sh + (size_t)b * NS * NS;
#pragma unroll
  for (int i = 0; i < 8; ++i)
#pragma unroll
    for (int j = 0; j < 4; ++j) {
      int rr = wr + 16 * i + 4 * fq;
      int cc = wc + 16 * j + fr;
      float ib = invB[cc];
#pragma unroll
      for (int p = 0; p < 4; ++p)
        Sb[(size_t)(tm + rr + p) * NS + tn + cc] =
            (_Float16)(acc[i][j][p] * invA[rr + p] * ib);
    }
}

// ---------------------------------------------------------------------------
// Kernel 4 (u/row step): 2048 blocks. first=1 -> W uniformly log(1/NS).
__global__ __launch_bounds__(256) void u_kernel(
    const _Float16* __restrict__ Sh, const float* __restrict__ W,
    float* __restrict__ U, float f, int first) {
  __shared__ float Wt[8][65];
  int blk = blockIdx.x;
  int bs = blk & 7, rest = blk >> 3;
  int rowgrp = rest & 31, bq = rest >> 5;
  int b = bq * 8 + bs;
  int t = threadIdx.x;
  if (!first) {
#pragma unroll
    for (int i = 0; i < 2; ++i) {
      int idx = t + 256 * i;
      Wt[idx & 7][idx >> 3] = W[b * NS + idx];
    }
    __syncthreads();
  }
  int w = t >> 6, l = t & 63;
  float wn[8];
#pragma unroll
  for (int e = 0; e < 8; ++e) wn[e] = first ? LOG_INV_NS : Wt[e][l];
  int m0 = rowgrp * 16 + w * 4;
  const _Float16* Sb = Sh + ((size_t)b * NS + m0) * NS + 8 * l;
  float sum[4] = {0.f, 0.f, 0.f, 0.f};
#pragma unroll
  for (int k = 0; k < 4; ++k) {
    half8 hv = *(const half8*)(Sb + (size_t)k * NS);
#pragma unroll
    for (int e = 0; e < 8; ++e) sum[k] += __expf(fmaf(f, (float)hv[e], wn[e]));
  }
#pragma unroll
  for (int o = 32; o; o >>= 1) {
#pragma unroll
    for (int k = 0; k < 4; ++k) sum[k] += __shfl_xor(sum[k], o, 64);
  }
  if (l == 0) {
#pragma unroll
    for (int k = 0; k < 4; ++k)
      U[b * NS + m0 + k] = LOG_INV_NS - __logf(sum[k]);
  }
}

// ---------------------------------------------------------------------------
// Kernel 5 (v/col step): 1024 blocks, high occupancy. first=1 -> vold = 0.
__global__ __launch_bounds__(256) void v_kernel(
    const _Float16* __restrict__ Sh, const float* __restrict__ U,
    float* __restrict__ V, float* __restrict__ W,
    float f, int first, int last, float* __restrict__ outPart) {
  __shared__ float Ul[NS];
  __shared__ float partC[64][33];
  __shared__ float partD[64][33];
  __shared__ float redC[4][33];
  __shared__ float redD[4][33];
  int blk = blockIdx.x;
  int b = blk & 63;
  int ng = blk >> 6;                // 0..15, 32 cols each
  int t = threadIdx.x;
  Ul[t] = U[b * NS + t];
  Ul[t + 256] = U[b * NS + t + 256];
  __syncthreads();

  int oct = t & 3;
  int mc = t >> 2;                  // m-chunk (8 rows), 0..63
  const _Float16* Sb = Sh + (size_t)b * NS * NS + (size_t)(mc * 8) * NS + ng * 32 + oct * 8;
  float c[8] = {}, d[8] = {};
#pragma unroll
  for (int i = 0; i < 8; ++i) {
    half8 hv = *(const half8*)(Sb + (size_t)i * NS);
    float um = Ul[mc * 8 + i];
#pragma unroll
    for (int e = 0; e < 8; ++e) {
      float sv = (float)hv[e];
      float ev = __expf(fmaf(f, sv, um));
      c[e] += ev;
      d[e] = fmaf(sv, ev, d[e]);
    }
  }
#pragma unroll
  for (int e = 0; e < 8; ++e) {
    partC[mc][oct * 8 + e] = c[e];
    partD[mc][oct * 8 + e] = d[e];
  }
  __syncthreads();
  {
    int ci = t & 31, seg = t >> 5;
    float cc = 0.f, dd = 0.f;
#pragma unroll
    for (int k = 0; k < 8; ++k) {
      cc += partC[seg * 8 + k][ci];
      dd += partD[seg * 8 + k][ci];
    }
    cc += __shfl_xor(cc, 32, 64);
    dd += __shfl_xor(dd, 32, 64);
    int w = t >> 6, l = t & 63;
    if (l < 32) { redC[w][l] = cc; redD[w][l] = dd; }
  }
  __syncthreads();
  if (t < 32) {
    float cc = redC[0][t] + redC[1][t] + redC[2][t] + redC[3][t];
    float vnew = LOG_INV_NS - __logf(cc);
    int n = b * NS + ng * 32 + t;
    float vold = first ? 0.f : V[n];
    V[n] = vnew;
    W[n] = 2.f * vnew - vold;
    if (last) {
      float dd = redD[0][t] + redD[1][t] + redD[2][t] + redD[3][t];
      float r = dd / cc;
      r += __shfl_xor(r, 16, 64);
      r += __shfl_xor(r, 8, 64);
      r += __shfl_xor(r, 4, 64);
      r += __shfl_xor(r, 2, 64);
      r += __shfl_xor(r, 1, 64);
      if (t == 0) outPart[b * 16 + ng] = r * (1.0f / (float)NS);
    }
  }
}

// ---------------------------------------------------------------------------
// Kernel 6: combine 16 partials per batch (deterministic)
__global__ void combine_kernel(const float* __restrict__ outPart, float* __restrict__ out) {
  int b = threadIdx.x;  // 64 threads
  float s = 0.f;
#pragma unroll
  for (int k = 0; k < 16; ++k) s += outPart[b * 16 + k];
  out[b] = s;
}

// ---------------------------------------------------------------------------
extern "C" void kernel_launch(void* const* d_in, const int* in_sizes, int n_in,
                              void* d_out, int out_size, void* d_ws, size_t ws_size,
                              hipStream_t stream) {
  (void)in_sizes; (void)n_in; (void)out_size; (void)ws_size;
  const float* x = (const float*)d_in[0];
  const float* y = (const float*)d_in[1];
  float* out = (float*)d_out;

  char* ws = (char*)d_ws;
  _Float16* Sh = (_Float16*)ws;                                // 32 MiB
  float* fregion = (float*)(ws + (size_t)NB * NS * NS * 2);
  float* U = fregion;                                          // 32768
  float* V = U + NB * NS;
  float* W = V + NB * NS;
  float* outPart = W + NB * NS;                                // 1024

  gemm_fused<<<256, 512, 0, stream>>>(x, y, Sh);

  for (int t = 1; t <= NITERS; ++t) {
    float f = 10.0f * (float)t;
    u_kernel<<<2048, 256, 0, stream>>>(Sh, W, U, f, t == 1 ? 1 : 0);
    v_kernel<<<1024, 256, 0, stream>>>(Sh, U, V, W, f, t == 1 ? 1 : 0,
                                       t == NITERS ? 1 : 0, outPart);
  }
  combine_kernel<<<1, 64, 0, stream>>>(outPart, out);
}

// Round 19
// 178.745 us; speedup vs baseline: 1.2077x; 1.2077x over previous
//
#include <hip/hip_runtime.h>
#include <hip/hip_fp16.h>

#define NB 64
#define NS 512
#define NH 1024
#define NITERS 10

// -log(512)
#define LOG_INV_NS (-6.238324625039508f)

using half8 = _Float16 __attribute__((ext_vector_type(8)));
using f32x4 = float __attribute__((ext_vector_type(4)));

// ---------------------------------------------------------------------------
// Fused GEMM (R16 verbatim, proven): batched cosine scores, f16 out.
// 256x256 tile, 512 thr / 8 waves, BK=64, LDS double-buffer, raw s_barrier,
// in-kernel row norms, epilogue normalization, XCD-pinned decode.
__global__ __launch_bounds__(512) void gemm_fused(
    const float* __restrict__ x, const float* __restrict__ y,
    _Float16* __restrict__ Sh) {
  __shared__ _Float16 As[2][256][72];
  __shared__ _Float16 Bs[2][256][72];
  __shared__ float invA[256], invB[256];

  int blk = blockIdx.x;
  int b = blk & 63;
  int tile = blk >> 6;
  int tm = (tile >> 1) * 256, tn = (tile & 1) * 256;
  int tid = threadIdx.x;
  int wid = tid >> 6, lane = tid & 63;
  int wr = (wid >> 2) * 128;
  int wc = (wid & 3) * 64;
  int fr = lane & 15, fq = lane >> 4;

  int srow = tid >> 1;
  int skh = (tid & 1) * 16;
  const float* xb = x + ((size_t)b * NS + tm + srow) * NH + skh;
  const float* yb = y + ((size_t)b * NS + tn + srow) * NH + skh;

  f32x4 acc[8][4] = {};
  float4 rx[4], ry[4];
  float sqx = 0.f, sqy = 0.f;

#define GLOAD(K0)                                                     \
  do {                                                                \
    const float4* px = (const float4*)(xb + (K0));                    \
    const float4* py = (const float4*)(yb + (K0));                    \
    rx[0] = px[0]; rx[1] = px[1]; rx[2] = px[2]; rx[3] = px[3];       \
    ry[0] = py[0]; ry[1] = py[1]; ry[2] = py[2]; ry[3] = py[3];       \
  } while (0)

#define CAST_WRITE(BUF, COL)                                          \
  do {                                                                \
    alignas(16) _Float16 ta[16];                                      \
    alignas(16) _Float16 tb[16];                                      \
    _Pragma("unroll") for (int j = 0; j < 4; ++j) {                   \
      float4 v = rx[j];                                               \
      ta[4 * j + 0] = (_Float16)v.x; ta[4 * j + 1] = (_Float16)v.y;   \
      ta[4 * j + 2] = (_Float16)v.z; ta[4 * j + 3] = (_Float16)v.w;   \
      sqx += v.x * v.x + v.y * v.y + v.z * v.z + v.w * v.w;           \
    }                                                                 \
    _Pragma("unroll") for (int j = 0; j < 4; ++j) {                   \
      float4 v = ry[j];                                               \
      tb[4 * j + 0] = (_Float16)v.x; tb[4 * j + 1] = (_Float16)v.y;   \
      tb[4 * j + 2] = (_Float16)v.z; tb[4 * j + 3] = (_Float16)v.w;   \
      sqy += v.x * v.x + v.y * v.y + v.z * v.z + v.w * v.w;           \
    }                                                                 \
    *(half8*)&As[BUF][srow][(COL) + skh + 0] = *(half8*)&ta[0];       \
    *(half8*)&As[BUF][srow][(COL) + skh + 8] = *(half8*)&ta[8];       \
    *(half8*)&Bs[BUF][srow][(COL) + skh + 0] = *(half8*)&tb[0];       \
    *(half8*)&Bs[BUF][srow][(COL) + skh + 8] = *(half8*)&tb[8];       \
  } while (0)

  GLOAD(0);
  CAST_WRITE(0, 0);
  GLOAD(32);
  CAST_WRITE(0, 32);
  GLOAD(64);
  asm volatile("s_waitcnt lgkmcnt(0)" ::: "memory");
  __builtin_amdgcn_sched_barrier(0);
  __builtin_amdgcn_s_barrier();
  __builtin_amdgcn_sched_barrier(0);

  for (int s = 0; s < 16; ++s) {
    int cur = s & 1;
    {
      half8 bf[4];
#pragma unroll
      for (int j = 0; j < 4; ++j)
        bf[j] = *(const half8*)&Bs[cur][wc + 16 * j + fr][8 * fq];
#pragma unroll
      for (int i = 0; i < 8; ++i) {
        half8 af = *(const half8*)&As[cur][wr + 16 * i + fr][8 * fq];
#pragma unroll
        for (int j = 0; j < 4; ++j)
          acc[i][j] = __builtin_amdgcn_mfma_f32_16x16x32_f16(af, bf[j], acc[i][j], 0, 0, 0);
      }
    }
    if (s < 15) {
      CAST_WRITE(cur ^ 1, 0);
      GLOAD((s + 1) * 64 + 32);
    }
    {
      half8 bf[4];
#pragma unroll
      for (int j = 0; j < 4; ++j)
        bf[j] = *(const half8*)&Bs[cur][wc + 16 * j + fr][32 + 8 * fq];
#pragma unroll
      for (int i = 0; i < 8; ++i) {
        half8 af = *(const half8*)&As[cur][wr + 16 * i + fr][32 + 8 * fq];
#pragma unroll
        for (int j = 0; j < 4; ++j)
          acc[i][j] = __builtin_amdgcn_mfma_f32_16x16x32_f16(af, bf[j], acc[i][j], 0, 0, 0);
      }
    }
    if (s < 15) {
      CAST_WRITE(cur ^ 1, 32);
      if (s < 14) GLOAD((s + 2) * 64);
    }
    asm volatile("s_waitcnt lgkmcnt(0)" ::: "memory");
    __builtin_amdgcn_sched_barrier(0);
    __builtin_amdgcn_s_barrier();
    __builtin_amdgcn_sched_barrier(0);
  }
#undef GLOAD
#undef CAST_WRITE

  sqx += __shfl_xor(sqx, 1, 64);
  sqy += __shfl_xor(sqy, 1, 64);
  if ((tid & 1) == 0) {
    invA[srow] = 1.0f / fmaxf(sqrtf(sqx), 1e-12f);
    invB[srow] = 1.0f / fmaxf(sqrtf(sqy), 1e-12f);
  }
  __syncthreads();

  _Float16* Sb = Sh + (size_t)b * NS * NS;
#pragma unroll
  for (int i = 0; i < 8; ++i)
#pragma unroll
    for (int j = 0; j < 4; ++j) {
      int rr = wr + 16 * i + 4 * fq;
      int cc = wc + 16 * j + fr;
      float ib = invB[cc];
#pragma unroll
      for (int p = 0; p < 4; ++p)
        Sb[(size_t)(tm + rr + p) * NS + tn + cc] =
            (_Float16)(acc[i][j][p] * invA[rr + p] * ib);
    }
}

// ---------------------------------------------------------------------------
// u_first: U_1[m] = -log512 - log( sum_n exp(10*S[m][n]) * (1/512) )
// (proven u_kernel body with W == LOG_INV_NS). 2048 blocks.
__global__ __launch_bounds__(256) void u_first_kernel(
    const _Float16* __restrict__ Sh, float* __restrict__ U, float f) {
  int blk = blockIdx.x;
  int bs = blk & 7, rest = blk >> 3;
  int rowgrp = rest & 31, bq = rest >> 5;
  int b = bq * 8 + bs;
  int t = threadIdx.x;
  int w = t >> 6, l = t & 63;
  int m0 = rowgrp * 16 + w * 4;
  const _Float16* Sb = Sh + ((size_t)b * NS + m0) * NS + 8 * l;
  float sum[4] = {0.f, 0.f, 0.f, 0.f};
#pragma unroll
  for (int k = 0; k < 4; ++k) {
    half8 hv = *(const half8*)(Sb + (size_t)k * NS);
#pragma unroll
    for (int e = 0; e < 8; ++e) sum[k] += __expf(fmaf(f, (float)hv[e], LOG_INV_NS));
  }
#pragma unroll
  for (int o = 32; o; o >>= 1) {
#pragma unroll
    for (int k = 0; k < 4; ++k) sum[k] += __shfl_xor(sum[k], o, 64);
  }
  if (l == 0) {
#pragma unroll
    for (int k = 0; k < 4; ++k)
      U[b * NS + m0 + k] = LOG_INV_NS - __logf(sum[k]);
  }
}

// ---------------------------------------------------------------------------
// P pass (iteration it): one S sweep does BOTH the v update AND the partial
// row sums for the NEXT iteration's u (S panel held in registers).
//   stage 1: c[n] = sum_m exp(f*S + U_it[m]); vnew; W_{it+1} = 2vnew - vold
//            (own 32 cols); on last, also d[n] and out partial.
//   stage 2: rowpart[b][ng][m] = sum_{n in own 32 cols} exp(fnext*S + W[n]).
// Prologue: U_it[m] = -log512 - log(sum_ng rowpart) (from prev pass), or
// from Ufirst when it==1. 1024 blocks (64 b x 16 col-groups), 256 thr.
__global__ __launch_bounds__(256) void p_kernel(
    const _Float16* __restrict__ Sh, const float* __restrict__ Ufirst,
    float* __restrict__ V, float* __restrict__ rowpart,
    float f, float fnext, int first, int last, float* __restrict__ outPart) {
  __shared__ float Ul[NS];
  __shared__ float partC[64][33];
  __shared__ float partD[64][33];
  __shared__ float redC[4][33];
  __shared__ float redD[4][33];
  __shared__ float Wl[32];
  __shared__ float partR[NS][5];

  int blk = blockIdx.x;
  int b = blk & 63;                 // blk%8 == b%8 (XCD-consistent with gemm)
  int ng = blk >> 6;                // 0..15, 32 cols each
  int t = threadIdx.x;
  int w = t >> 6, l = t & 63;

  // ---- prologue: U for this iteration ----
  if (first) {
    Ul[t] = Ufirst[b * NS + t];
    Ul[t + 256] = Ufirst[b * NS + t + 256];
  } else {
    const float* rp = rowpart + (size_t)b * 16 * NS;
    float s0 = 0.f, s1 = 0.f;
#pragma unroll
    for (int k = 0; k < 16; ++k) {
      s0 += rp[k * NS + t];
      s1 += rp[k * NS + t + 256];
    }
    Ul[t] = LOG_INV_NS - __logf(s0);
    Ul[t + 256] = LOG_INV_NS - __logf(s1);
  }
  __syncthreads();

  // ---- load S panel into registers (proven v_kernel geometry) ----
  int oct = t & 3;
  int mc = t >> 2;                  // m-chunk (8 rows), 0..63
  const _Float16* Sbc = Sh + (size_t)b * NS * NS + (size_t)(mc * 8) * NS + ng * 32 + oct * 8;
  half8 hv[8];
#pragma unroll
  for (int i = 0; i < 8; ++i) hv[i] = *(const half8*)(Sbc + (size_t)i * NS);

  // ---- stage 1: col sums ----
  float c[8] = {}, d[8] = {};
  if (!last) {
#pragma unroll
    for (int i = 0; i < 8; ++i) {
      float um = Ul[mc * 8 + i];
#pragma unroll
      for (int e = 0; e < 8; ++e)
        c[e] += __expf(fmaf(f, (float)hv[i][e], um));
    }
  } else {
#pragma unroll
    for (int i = 0; i < 8; ++i) {
      float um = Ul[mc * 8 + i];
#pragma unroll
      for (int e = 0; e < 8; ++e) {
        float sv = (float)hv[i][e];
        float ev = __expf(fmaf(f, sv, um));
        c[e] += ev;
        d[e] = fmaf(sv, ev, d[e]);
      }
    }
  }
#pragma unroll
  for (int e = 0; e < 8; ++e) {
    partC[mc][oct * 8 + e] = c[e];
    if (last) partD[mc][oct * 8 + e] = d[e];
  }
  __syncthreads();
  {
    int ci = t & 31, seg = t >> 5;
    float cc = 0.f, dd = 0.f;
#pragma unroll
    for (int k = 0; k < 8; ++k) {
      cc += partC[seg * 8 + k][ci];
      if (last) dd += partD[seg * 8 + k][ci];
    }
    cc += __shfl_xor(cc, 32, 64);
    if (last) dd += __shfl_xor(dd, 32, 64);
    if (l < 32) { redC[w][l] = cc; if (last) redD[w][l] = dd; }
  }
  __syncthreads();
  if (t < 32) {
    float cc = redC[0][t] + redC[1][t] + redC[2][t] + redC[3][t];
    if (!last) {
      float vnew = LOG_INV_NS - __logf(cc);
      int n = b * NS + ng * 32 + t;
      float vold = first ? 0.f : V[n];
      V[n] = vnew;
      Wl[t] = 2.f * vnew - vold;
    } else {
      float dd = redD[0][t] + redD[1][t] + redD[2][t] + redD[3][t];
      float r = dd / cc;
      r += __shfl_xor(r, 16, 64);
      r += __shfl_xor(r, 8, 64);
      r += __shfl_xor(r, 4, 64);
      r += __shfl_xor(r, 2, 64);
      r += __shfl_xor(r, 1, 64);
      if (t == 0) outPart[b * 16 + ng] = r * (1.0f / (float)NS);
    }
  }
  if (last) return;
  __syncthreads();

  // ---- stage 2: partial row sums for next iteration's u ----
  float wl[8];
#pragma unroll
  for (int e = 0; e < 8; ++e) wl[e] = Wl[oct * 8 + e];
#pragma unroll
  for (int i = 0; i < 8; ++i) {
    float s = 0.f;
#pragma unroll
    for (int e = 0; e < 8; ++e)
      s += __expf(fmaf(fnext, (float)hv[i][e], wl[e]));
    partR[mc * 8 + i][oct] = s;
  }
  __syncthreads();
  {
    float* rp = rowpart + ((size_t)b * 16 + ng) * NS;
    float q0 = partR[t][0] + partR[t][1] + partR[t][2] + partR[t][3];
    float q1 = partR[t + 256][0] + partR[t + 256][1] + partR[t + 256][2] + partR[t + 256][3];
    rp[t] = q0;
    rp[t + 256] = q1;
  }
}

// ---------------------------------------------------------------------------
// combine 16 partials per batch (deterministic)
__global__ void combine_kernel(const float* __restrict__ outPart, float* __restrict__ out) {
  int b = threadIdx.x;  // 64 threads
  float s = 0.f;
#pragma unroll
  for (int k = 0; k < 16; ++k) s += outPart[b * 16 + k];
  out[b] = s;
}

// ---------------------------------------------------------------------------
extern "C" void kernel_launch(void* const* d_in, const int* in_sizes, int n_in,
                              void* d_out, int out_size, void* d_ws, size_t ws_size,
                              hipStream_t stream) {
  (void)in_sizes; (void)n_in; (void)out_size; (void)ws_size;
  const float* x = (const float*)d_in[0];
  const float* y = (const float*)d_in[1];
  float* out = (float*)d_out;

  char* ws = (char*)d_ws;
  _Float16* Sh = (_Float16*)ws;                                // 32 MiB
  float* fregion = (float*)(ws + (size_t)NB * NS * NS * 2);
  float* U = fregion;                                          // 32768
  float* V = U + NB * NS;                                      // 32768
  float* outPart = V + NB * NS;                                // 1024
  float* rowpart = outPart + 1024;                             // 64*16*512 = 524288

  gemm_fused<<<256, 512, 0, stream>>>(x, y, Sh);
  u_first_kernel<<<2048, 256, 0, stream>>>(Sh, U, 10.0f);

  for (int t = 1; t <= NITERS; ++t) {
    p_kernel<<<1024, 256, 0, stream>>>(Sh, U, V, rowpart,
                                       10.0f * (float)t, 10.0f * (float)(t + 1),
                                       t == 1 ? 1 : 0, t == NITERS ? 1 : 0,
                                       outPart);
  }
  combine_kernel<<<1, 64, 0, stream>>>(outPart, out);
}